// Round 5
// baseline (120.823 us; speedup 1.0000x reference)
//
#include <hip/hip_runtime.h>
#include <math.h>

#define BATCH 4
#define SEQ   4096
#define EMB   1024
#define HDIM  64

typedef __attribute__((ext_vector_type(8))) short bf16x8;
typedef __attribute__((ext_vector_type(4))) float f32x4;

#define MFMA16(a, b, c) __builtin_amdgcn_mfma_f32_16x16x32_bf16(a, b, c, 0, 0, 0)

__device__ __forceinline__ unsigned short f2bf(float f) {
  unsigned int u = __float_as_uint(f);
  u = (u + 0x7FFFu + ((u >> 16) & 1u)) >> 16;   // RNE
  return (unsigned short)u;
}

__device__ __forceinline__ float fexp2(float x) {  // 2^x, hw v_exp_f32
  float r;
  asm("v_exp_f32 %0, %1" : "=v"(r) : "v"(x));
  return r;
}

// ---- W -> MFMA B-fragment order: wtf[frag(c16,kw)][lane*8+e] bf16 -----------
// frag element (lane=g*16+p, e) = W^T[c16*16+p][kw*32+8g+e]. 48 blocks.
__global__ __launch_bounds__(256) void wt_kernel(
    const float* __restrict__ Wq, const float* __restrict__ Wk,
    const float* __restrict__ Wv, unsigned short* __restrict__ wtf) {
  __shared__ float tile[64][65];
  const int bid = blockIdx.x;           // 48 = 3 matrices x 16 k-tiles
  const int m = bid >> 4, kt = bid & 15;
  const float* W = (m == 0) ? Wq : (m == 1) ? Wk : Wv;
  const int tid = threadIdx.x;
  {
    const int r = tid >> 2, c4 = tid & 3;
    const float* src = W + (size_t)(kt * 64 + r) * 64 + c4 * 16;
#pragma unroll
    for (int j = 0; j < 4; ++j) {
      float4 a = *(const float4*)(src + j * 4);
      tile[r][c4 * 16 + j * 4 + 0] = a.x;
      tile[r][c4 * 16 + j * 4 + 1] = a.y;
      tile[r][c4 * 16 + j * 4 + 2] = a.z;
      tile[r][c4 * 16 + j * 4 + 3] = a.w;
    }
  }
  __syncthreads();
  const int lane = tid & 63, fct = tid >> 6;     // col-tile 0..3 within matrix
  const int g = lane >> 4, p = lane & 15;
#pragma unroll
  for (int u = 0; u < 2; ++u) {
    unsigned short o8[8];
#pragma unroll
    for (int e = 0; e < 8; ++e) o8[e] = f2bf(tile[u * 32 + 8 * g + e][fct * 16 + p]);
    const int c16 = m * 4 + fct, kw = kt * 2 + u;
    *(bf16x8*)(wtf + (size_t)(c16 * 32 + kw) * 512 + lane * 8) = *(bf16x8*)o8;
  }
}

// ---- QKV projection via MFMA: 16-row M-tiles, W-frags direct from L2 --------
__global__ __launch_bounds__(256) void qkv_mfma_kernel(
    const float* __restrict__ x, const unsigned short* __restrict__ wtf,
    unsigned short* __restrict__ qb, unsigned short* __restrict__ kb,
    unsigned short* __restrict__ vt) {
  __shared__ __align__(16) unsigned short xs[16 * 64];   // swizzled [row][k]
  const int tid  = threadIdx.x;
  const int lane = tid & 63, wid = tid >> 6;
  const int g = lane >> 4, p = lane & 15;
  const size_t row0 = (size_t)blockIdx.x * 16;

  const int sr = tid >> 4, sc = tid & 15;                // x: row, 4-k group
  const float* xp = x + (row0 + sr) * EMB + sc * 4;

  f32x4 acc[3];
#pragma unroll
  for (int ct = 0; ct < 3; ++ct) acc[ct] = (f32x4){0.f, 0.f, 0.f, 0.f};

  float4 rx = *(const float4*)xp;
  bf16x8 rw[6];
#pragma unroll
  for (int ct = 0; ct < 3; ++ct)
#pragma unroll
    for (int u = 0; u < 2; ++u)
      rw[ct * 2 + u] = *(const bf16x8*)(wtf + (size_t)((wid * 3 + ct) * 32 + u) * 512 + lane * 8);

  for (int kc = 0; kc < 16; ++kc) {
    __syncthreads();                   // prev chunk's xs reads done
    {
      ushort4 h;
      h.x = f2bf(rx.x); h.y = f2bf(rx.y); h.z = f2bf(rx.z); h.w = f2bf(rx.w);
      *(ushort4*)((char*)xs + ((sr * 128 + sc * 8) ^ ((sr & 7) << 4))) = h;
    }
    float4 rxn;
    bf16x8 rwn[6];
    if (kc < 15) {                     // prefetch next chunk under compute
      rxn = *(const float4*)(xp + (kc + 1) * 64);
#pragma unroll
      for (int ct = 0; ct < 3; ++ct)
#pragma unroll
        for (int u = 0; u < 2; ++u)
          rwn[ct * 2 + u] = *(const bf16x8*)(wtf +
              (size_t)((wid * 3 + ct) * 32 + (kc + 1) * 2 + u) * 512 + lane * 8);
    }
    __syncthreads();                   // xs ready
#pragma unroll
    for (int ks = 0; ks < 2; ++ks) {
      bf16x8 af = *(const bf16x8*)((char*)xs +
                  ((p * 128 + ks * 64 + g * 16) ^ ((p & 7) << 4)));
#pragma unroll
      for (int ct = 0; ct < 3; ++ct)
        acc[ct] = MFMA16(af, rw[ct * 2 + ks], acc[ct]);
    }
    rx = rxn;
#pragma unroll
    for (int i = 0; i < 6; ++i) rw[i] = rwn[i];
  }

  // epilogue: D[row=4g+r][col=16ct+p]; q gets C^-0.5 * log2(e) folded in
  const int b     = (int)(row0 >> 12);
  const int tbase = (int)(row0 & 4095);
#pragma unroll
  for (int ct = 0; ct < 3; ++ct) {
    const int c0  = wid * 48 + ct * 16;
    const int mtx = c0 >> 6;
    const int col = (c0 & 63) + p;
#pragma unroll
    for (int r = 0; r < 4; ++r) {
      const int row = 4 * g + r;
      const float vf = acc[ct][r];
      if (mtx == 0)      qb[(row0 + row) * HDIM + col] = f2bf(vf * 0.0450843714f);
      else if (mtx == 1) kb[(row0 + row) * HDIM + col] = f2bf(vf);
      else vt[(((size_t)b * 64 + (tbase >> 6)) * 64 + col) * 64 + (tbase & 63) + row] = f2bf(vf);
    }
  }
}

// ---- MFMA flash attention: KVBLK=128, LDS P-transpose, defer-max, exp2 ------
__global__ __launch_bounds__(256) void attn_kernel(
    const unsigned short* __restrict__ qb, const unsigned short* __restrict__ kbm,
    const unsigned short* __restrict__ vt, float* __restrict__ out) {
  __shared__ float msh[4][16], lsh[4][16];
  __shared__ float osh[4][64][17];
  __shared__ __align__(16) unsigned short plds[4][2048];  // per-wave [16q][128k] swz
  const int wid  = threadIdx.x >> 6;
  const int lane = threadIdx.x & 63;
  const int g = lane >> 4, p = lane & 15;
  const int bid = blockIdx.x, batch = bid >> 8;
  int w = bid & 255;
  if (batch & 1) w = 255 - w;                 // causal load balance
  const int tq0 = w * 16;
  const size_t grow0 = (size_t)batch * SEQ + tq0;
  const int mbd = w >> 3;                     // diagonal 128-key macro tile

  const unsigned short* qrow = qb + (grow0 + p) * HDIM;
  const bf16x8 qf0 = *(const bf16x8*)(qrow + 8 * g);
  const bf16x8 qf1 = *(const bf16x8*)(qrow + 32 + 8 * g);

  const unsigned short* kbase = kbm + (size_t)batch * SEQ * HDIM;
  const unsigned short* vbase = vt  + (size_t)batch * SEQ * HDIM;
  char* const mypb = (char*)&plds[wid][0];

  float m = -1e30f, l = 0.f;
  f32x4 o[4];
#pragma unroll
  for (int mi = 0; mi < 4; ++mi) o[mi] = (f32x4){0.f, 0.f, 0.f, 0.f};

  for (int mt = wid; mt <= mbd; mt += 4) {
    // ---- S^T = K . Q^T over 128 keys (scores pre-scaled to log2 domain) ----
    const unsigned short* kp = kbase + ((size_t)(mt * 128 + p)) * HDIM + 8 * g;
    f32x4 s[8];
#pragma unroll
    for (int i = 0; i < 8; ++i) {
      bf16x8 a0 = *(const bf16x8*)(kp + i * 1024);
      bf16x8 a1 = *(const bf16x8*)(kp + i * 1024 + 32);
      f32x4 a = (f32x4){0.f, 0.f, 0.f, 0.f};
      a = MFMA16(a0, qf0, a);
      a = MFMA16(a1, qf1, a);
      s[i] = a;
    }
    if (mt == mbd) {                          // causal mask, diagonal macro only
#pragma unroll
      for (int i = 0; i < 8; ++i)
#pragma unroll
        for (int r = 0; r < 4; ++r) {
          int key = mt * 128 + 16 * i + 4 * g + r;
          if (key > tq0 + p) s[i][r] = -1e30f;
        }
    }
    // ---- tile max (per query col p) ----
    float tm = -3e38f;
#pragma unroll
    for (int i = 0; i < 8; ++i)
#pragma unroll
      for (int r = 0; r < 4; ++r) tm = fmaxf(tm, s[i][r]);
    tm = fmaxf(tm, __shfl_xor(tm, 16));
    tm = fmaxf(tm, __shfl_xor(tm, 32));
    // ---- defer-max (T13): rescale only if max grew past threshold ----
    if (__any(tm > m + 11.5f)) {
      float mn = fmaxf(m, tm);
      float c = fexp2(m - mn);
      l *= c;
#pragma unroll
      for (int mi = 0; mi < 4; ++mi) o[mi] *= c;
      m = mn;
    }
    // ---- P = exp2(S - m); pack bf16 -> per-wave swizzled LDS ----
    float psum = 0.f;
#pragma unroll
    for (int i = 0; i < 8; ++i) {
      float p0 = fexp2(s[i][0] - m), p1 = fexp2(s[i][1] - m);
      float p2 = fexp2(s[i][2] - m), p3 = fexp2(s[i][3] - m);
      psum += (p0 + p1) + (p2 + p3);
      ushort4 h;
      h.x = f2bf(p0); h.y = f2bf(p1); h.z = f2bf(p2); h.w = f2bf(p3);
      *(ushort4*)(mypb + ((p * 256 + i * 32 + 8 * g) ^ ((p & 7) << 4))) = h;
    }
    l += psum;
    asm volatile("s_waitcnt lgkmcnt(0)" ::: "memory");
    __builtin_amdgcn_sched_barrier(0);
    // ---- read P^T B-frags: col=p, k=8g+e per 32-key window ----
    bf16x8 bq[4];
#pragma unroll
    for (int ks = 0; ks < 4; ++ks)
      bq[ks] = *(const bf16x8*)(mypb + ((p * 256 + ks * 64 + 16 * g) ^ ((p & 7) << 4)));
    // ---- O^T += V^T . P^T ----
#pragma unroll
    for (int mi = 0; mi < 4; ++mi) {
      const unsigned short* vq = vbase + (size_t)(mt * 2) * 4096 + (16 * mi + p) * 64 + 8 * g;
      bf16x8 v0 = *(const bf16x8*)(vq);
      bf16x8 v1 = *(const bf16x8*)(vq + 32);
      bf16x8 v2 = *(const bf16x8*)(vq + 4096);
      bf16x8 v3 = *(const bf16x8*)(vq + 4096 + 32);
      o[mi] = MFMA16(v0, bq[0], o[mi]);
      o[mi] = MFMA16(v1, bq[1], o[mi]);
      o[mi] = MFMA16(v2, bq[2], o[mi]);
      o[mi] = MFMA16(v3, bq[3], o[mi]);
    }
  }

  // ---- merge the 4 key-split partials (log2-domain maxes) ----
  l += __shfl_xor(l, 16);
  l += __shfl_xor(l, 32);
  if (g == 0) { msh[wid][p] = m; lsh[wid][p] = l; }
#pragma unroll
  for (int mi = 0; mi < 4; ++mi)
#pragma unroll
    for (int r = 0; r < 4; ++r) osh[wid][16 * mi + 4 * g + r][p] = o[mi][r];
  __syncthreads();

  const int q  = threadIdx.x & 15;
  const int db = threadIdx.x >> 4;
  float mm = fmaxf(fmaxf(msh[0][q], msh[1][q]), fmaxf(msh[2][q], msh[3][q]));
  float L = 0.f, a0 = 0.f, a1 = 0.f, a2 = 0.f, a3 = 0.f;
#pragma unroll
  for (int wv = 0; wv < 4; ++wv) {
    float sc = fexp2(msh[wv][q] - mm);
    L  += lsh[wv][q] * sc;
    a0 += osh[wv][4 * db + 0][q] * sc;
    a1 += osh[wv][4 * db + 1][q] * sc;
    a2 += osh[wv][4 * db + 2][q] * sc;
    a3 += osh[wv][4 * db + 3][q] * sc;
  }
  const float inv = 1.f / L;
  float* op = out + (grow0 + q) * HDIM + 4 * db;
  op[0] = a0 * inv; op[1] = a1 * inv; op[2] = a2 * inv; op[3] = a3 * inv;
}

extern "C" void kernel_launch(void* const* d_in, const int* in_sizes, int n_in,
                              void* d_out, int out_size, void* d_ws, size_t ws_size,
                              hipStream_t stream) {
  const float* x  = (const float*)d_in[0];
  const float* Wq = (const float*)d_in[1];
  const float* Wk = (const float*)d_in[2];
  const float* Wv = (const float*)d_in[3];
  float* outp = (float*)d_out;

  const size_t rows = (size_t)BATCH * SEQ;        // 16384
  unsigned short* qbf = (unsigned short*)d_ws;
  unsigned short* kbf = qbf + rows * HDIM;
  unsigned short* vtb = kbf + rows * HDIM;
  unsigned short* wtf = vtb + rows * HDIM;        // 192K bf16 frag-ordered W

  wt_kernel<<<dim3(48), dim3(256), 0, stream>>>(Wq, Wk, Wv, wtf);
  qkv_mfma_kernel<<<dim3((unsigned)(rows / 16)), dim3(256), 0, stream>>>(x, wtf, qbf, kbf, vtb);
  attn_kernel<<<dim3((unsigned)(rows / 16)), dim3(256), 0, stream>>>(qbf, kbf, vtb, outp);
}

// Round 6
// 120.318 us; speedup vs baseline: 1.0042x; 1.0042x over previous
//
#include <hip/hip_runtime.h>
#include <math.h>

#define BATCH 4
#define SEQ   4096
#define EMB   1024
#define HDIM  64

typedef __attribute__((ext_vector_type(8))) short bf16x8;
typedef __attribute__((ext_vector_type(4))) float f32x4;

#define MFMA16(a, b, c) __builtin_amdgcn_mfma_f32_16x16x32_bf16(a, b, c, 0, 0, 0)

__device__ __forceinline__ unsigned short f2bf(float f) {
  unsigned int u = __float_as_uint(f);
  u = (u + 0x7FFFu + ((u >> 16) & 1u)) >> 16;   // RNE
  return (unsigned short)u;
}

__device__ __forceinline__ float fexp2(float x) {  // 2^x, hw v_exp_f32
  float r;
  asm("v_exp_f32 %0, %1" : "=v"(r) : "v"(x));
  return r;
}

// ---------------- W pre-transpose: W[1024][64] f32 x3 -> Wt[192][1024] bf16 --
__global__ __launch_bounds__(256) void wt_kernel(
    const float* __restrict__ Wq, const float* __restrict__ Wk,
    const float* __restrict__ Wv, unsigned short* __restrict__ wt) {
  __shared__ float tile[64][65];
  const int bid = blockIdx.x;           // 48 = 3 matrices x 16 k-tiles
  const int m = bid >> 4, kt = bid & 15;
  const float* W = (m == 0) ? Wq : (m == 1) ? Wk : Wv;
  const int tid = threadIdx.x;
  {
    const int r = tid >> 2, c4 = tid & 3;          // k-row, 16-col group
    const float* src = W + (size_t)(kt * 64 + r) * 64 + c4 * 16;
#pragma unroll
    for (int j = 0; j < 4; ++j) {
      float4 a = *(const float4*)(src + j * 4);
      tile[r][c4 * 16 + j * 4 + 0] = a.x;
      tile[r][c4 * 16 + j * 4 + 1] = a.y;
      tile[r][c4 * 16 + j * 4 + 2] = a.z;
      tile[r][c4 * 16 + j * 4 + 3] = a.w;
    }
  }
  __syncthreads();
  {
    const int col = tid >> 2, kq = tid & 3;        // out col, 16-k group
    unsigned short o[16];
#pragma unroll
    for (int j = 0; j < 16; ++j) o[j] = f2bf(tile[kq * 16 + j][col]);
    unsigned short* dst = wt + (size_t)(m * 64 + col) * 1024 + kt * 64 + kq * 16;
    *(bf16x8*)(dst)     = *(bf16x8*)&o[0];
    *(bf16x8*)(dst + 8) = *(bf16x8*)&o[8];
  }
}

// ---------------- QKV projection via MFMA (round-4 proven version) ----------
// 512 blocks (2/CU): 32-row M-tile x all 192 cols. K chunks of 64, bf16 in
// XOR-swizzled LDS; reg-prefetch of next chunk. Wave w owns cols 48w..48w+47.
// q output additionally scaled by C^-0.5 * log2(e) (attention runs in exp2).
__global__ __launch_bounds__(256) void qkv_mfma_kernel(
    const float* __restrict__ x, const unsigned short* __restrict__ wt,
    unsigned short* __restrict__ qb, unsigned short* __restrict__ kb,
    unsigned short* __restrict__ vt) {
  __shared__ __align__(16) unsigned short xs[32 * 64];   // [row][k] swizzled
  __shared__ __align__(16) unsigned short ws[192 * 64];  // [col][k] swizzled
  const int tid  = threadIdx.x;
  const int lane = tid & 63, wid = tid >> 6;
  const int g = lane >> 4, p = lane & 15;
  const size_t row0 = (size_t)blockIdx.x * 32;

  const int sr = tid >> 3, sc = tid & 7;                 // x: row, 8-k group
  const float* xp = x + (row0 + sr) * EMB + sc * 8;

  f32x4 acc[2][3];
#pragma unroll
  for (int rt = 0; rt < 2; ++rt)
#pragma unroll
    for (int ct = 0; ct < 3; ++ct) acc[rt][ct] = (f32x4){0.f, 0.f, 0.f, 0.f};

  float4 rx[2];
  bf16x8 rw[6];
#pragma unroll
  for (int j = 0; j < 2; ++j) rx[j] = *(const float4*)(xp + j * 4);
#pragma unroll
  for (int it = 0; it < 6; ++it) {
    int i = tid + it * 256, col = i >> 3, cc = i & 7;
    rw[it] = *(const bf16x8*)(wt + (size_t)col * 1024 + cc * 8);
  }

  for (int kc = 0; kc < 16; ++kc) {
    __syncthreads();                       // previous chunk's reads done
#pragma unroll
    for (int j = 0; j < 2; ++j) {
      ushort4 h;
      h.x = f2bf(rx[j].x); h.y = f2bf(rx[j].y);
      h.z = f2bf(rx[j].z); h.w = f2bf(rx[j].w);
      *(ushort4*)((char*)xs + ((sr * 128 + sc * 16 + j * 8) ^ ((sr & 7) << 4))) = h;
    }
#pragma unroll
    for (int it = 0; it < 6; ++it) {
      int i = tid + it * 256, col = i >> 3, cc = i & 7;
      *(bf16x8*)((char*)ws + ((col * 128 + cc * 16) ^ ((col & 7) << 4))) = rw[it];
    }
    if (kc < 15) {
      const float* xpn = xp + (kc + 1) * 64;
#pragma unroll
      for (int j = 0; j < 2; ++j) rx[j] = *(const float4*)(xpn + j * 4);
#pragma unroll
      for (int it = 0; it < 6; ++it) {
        int i = tid + it * 256, col = i >> 3, cc = i & 7;
        rw[it] = *(const bf16x8*)(wt + (size_t)col * 1024 + (kc + 1) * 64 + cc * 8);
      }
    }
    __syncthreads();
#pragma unroll
    for (int ks = 0; ks < 2; ++ks) {
      bf16x8 af[2];
#pragma unroll
      for (int rt = 0; rt < 2; ++rt) {
        int row = rt * 16 + p;
        af[rt] = *(const bf16x8*)((char*)xs +
                 ((row * 128 + ks * 64 + g * 16) ^ ((row & 7) << 4)));
      }
#pragma unroll
      for (int ct = 0; ct < 3; ++ct) {
        int col = wid * 48 + ct * 16 + p;
        bf16x8 bfr = *(const bf16x8*)((char*)ws +
                     ((col * 128 + ks * 64 + g * 16) ^ ((col & 7) << 4)));
#pragma unroll
        for (int rt = 0; rt < 2; ++rt)
          acc[rt][ct] = MFMA16(af[rt], bfr, acc[rt][ct]);
      }
    }
  }

  const int b     = (int)(row0 >> 12);
  const int tbase = (int)(row0 & 4095);
  unsigned short* vtb = vt + (((size_t)b * 64 + (tbase >> 6)) * 64) * 64 + (tbase & 63);
#pragma unroll
  for (int rt = 0; rt < 2; ++rt)
#pragma unroll
    for (int ct = 0; ct < 3; ++ct) {
      const int c0  = wid * 48 + ct * 16;
      const int mtx = c0 >> 6;
      const int col = (c0 & 63) + p;
#pragma unroll
      for (int r = 0; r < 4; ++r) {
        const int row = rt * 16 + 4 * g + r;
        const float vf = acc[rt][ct][r];
        if (mtx == 0)      qb[(row0 + row) * HDIM + col] = f2bf(vf * 0.0450843714f);
        else if (mtx == 1) kb[(row0 + row) * HDIM + col] = f2bf(vf);
        else               vtb[(size_t)col * 64 + row]   = f2bf(vf);
      }
    }
}

// ---------------- MFMA flash attention (round-4 base + latency fixes) -------
// Block = 4 waves sharing 16 queries; wave wid takes key tiles kt=wid,wid+4,...
// XCD remap: xcd=bid&7 owns batch xcd>>1 (K+V 1MB -> L2-resident); w parity =
// xcd&1 balances causal work across XCDs; complement idx pairing in time.
// Reg double-buffer next K tile; V loads issued before softmax. exp2 domain,
// defer-max (T13). Shuffle-based P^T transpose (proven round 4).
__global__ __launch_bounds__(256) void attn_kernel(
    const unsigned short* __restrict__ qb, const unsigned short* __restrict__ kbm,
    const unsigned short* __restrict__ vt, float* __restrict__ out) {
  __shared__ float msh[4][16], lsh[4][16];
  __shared__ float osh[4][64][17];
  const int wid  = threadIdx.x >> 6;
  const int lane = threadIdx.x & 63;
  const int g = lane >> 4, p = lane & 15;
  const int bid = blockIdx.x;
  const int xcd = bid & 7, idx = bid >> 3;
  const int batch = xcd >> 1;
  const int wb = (idx & 1) ? (127 - (idx >> 1)) : (idx >> 1);
  const int w  = (wb << 1) | (xcd & 1);
  const int tq0 = w * 16;
  const size_t grow0 = (size_t)batch * SEQ + tq0;
  const int kbd = w >> 2;

  const unsigned short* qrow = qb + (grow0 + p) * HDIM;
  const bf16x8 qf0 = *(const bf16x8*)(qrow + 8 * g);
  const bf16x8 qf1 = *(const bf16x8*)(qrow + 32 + 8 * g);

  const unsigned short* kbase = kbm + (size_t)batch * SEQ * HDIM;
  const unsigned short* vbase = vt  + (size_t)batch * SEQ * HDIM;

  const int srcA = (g & 1) * 32 + p;
  const int srcB = srcA + 16;
  const bool hi = (g >> 1) != 0;

  float m = -1e30f, l = 0.f;
  f32x4 o[4];
#pragma unroll
  for (int mi = 0; mi < 4; ++mi) o[mi] = (f32x4){0.f, 0.f, 0.f, 0.f};

  // prologue: load K frags for first tile (always in-bounds)
  bf16x8 ka[8];
  {
    const unsigned short* kp = kbase + ((size_t)(wid * 64 + p)) * HDIM + 8 * g;
#pragma unroll
    for (int t = 0; t < 4; ++t) {
      ka[2 * t]     = *(const bf16x8*)(kp + t * 1024);
      ka[2 * t + 1] = *(const bf16x8*)(kp + t * 1024 + 32);
    }
  }

  for (int kt = wid; kt <= kbd; kt += 4) {
    // ---- issue next K tile loads (hidden under this tile's compute) ----
    bf16x8 kn[8];
    const bool more = (kt + 4 <= kbd);
    if (more) {
      const unsigned short* kp = kbase + ((size_t)((kt + 4) * 64 + p)) * HDIM + 8 * g;
#pragma unroll
      for (int t = 0; t < 4; ++t) {
        kn[2 * t]     = *(const bf16x8*)(kp + t * 1024);
        kn[2 * t + 1] = *(const bf16x8*)(kp + t * 1024 + 32);
      }
    }
    // ---- issue V loads now; consumed after softmax (latency hidden) ----
    bf16x8 va[8];
    {
      const unsigned short* vp = vbase + (size_t)kt * 4096 + p * 64 + 8 * g;
#pragma unroll
      for (int mi = 0; mi < 4; ++mi) {
        va[2 * mi]     = *(const bf16x8*)(vp + mi * 1024);
        va[2 * mi + 1] = *(const bf16x8*)(vp + mi * 1024 + 32);
      }
    }
    // ---- S^T = K . Q^T (scores in log2 domain; scale folded into q) ----
    f32x4 s[4];
#pragma unroll
    for (int t = 0; t < 4; ++t) {
      f32x4 a = (f32x4){0.f, 0.f, 0.f, 0.f};
      a = MFMA16(ka[2 * t], qf0, a);
      a = MFMA16(ka[2 * t + 1], qf1, a);
      s[t] = a;
    }
    // ---- causal mask (diag tile only) ----
    if (kt == kbd) {
#pragma unroll
      for (int t = 0; t < 4; ++t)
#pragma unroll
        for (int r = 0; r < 4; ++r) {
          int key = kt * 64 + 16 * t + 4 * g + r;
          if (key > tq0 + p) s[t][r] = -1e30f;
        }
    }
    // ---- tile max ----
    float tm = -3e38f;
#pragma unroll
    for (int t = 0; t < 4; ++t)
#pragma unroll
      for (int r = 0; r < 4; ++r) tm = fmaxf(tm, s[t][r]);
    tm = fmaxf(tm, __shfl_xor(tm, 16));
    tm = fmaxf(tm, __shfl_xor(tm, 32));
    // ---- defer-max (T13): rescale only if max grew past threshold ----
    if (__any(tm > m + 11.5f)) {
      float mn = fmaxf(m, tm);
      float c = fexp2(m - mn);
      l *= c;
#pragma unroll
      for (int mi = 0; mi < 4; ++mi) o[mi] *= c;
      m = mn;
    }
    // ---- P = exp2(S - m) ----
    float psum = 0.f;
#pragma unroll
    for (int t = 0; t < 4; ++t)
#pragma unroll
      for (int r = 0; r < 4; ++r) {
        float pv = fexp2(s[t][r] - m);
        s[t][r] = pv;
        psum += pv;
      }
    l += psum;
    // ---- P^T -> B-operand fragments via shuffles (round-4 proven) ----
    bf16x8 b0, b1;
#pragma unroll
    for (int r = 0; r < 4; ++r) {
      float v0 = __shfl(s[0][r], srcA), v1 = __shfl(s[1][r], srcA);
      float v2 = __shfl(s[0][r], srcB), v3 = __shfl(s[1][r], srcB);
      b0[r]     = (short)f2bf(hi ? v1 : v0);
      b0[4 + r] = (short)f2bf(hi ? v3 : v2);
      float u0 = __shfl(s[2][r], srcA), u1 = __shfl(s[3][r], srcA);
      float u2 = __shfl(s[2][r], srcB), u3 = __shfl(s[3][r], srcB);
      b1[r]     = (short)f2bf(hi ? u1 : u0);
      b1[4 + r] = (short)f2bf(hi ? u3 : u2);
    }
    // ---- O^T += V^T . P^T ----
#pragma unroll
    for (int mi = 0; mi < 4; ++mi) {
      o[mi] = MFMA16(va[2 * mi], b0, o[mi]);
      o[mi] = MFMA16(va[2 * mi + 1], b1, o[mi]);
    }
    // ---- rotate K double-buffer ----
    if (more) {
#pragma unroll
      for (int i = 0; i < 8; ++i) ka[i] = kn[i];
    }
  }

  // ---- merge the 4 key-split partials (log2-domain maxes) ----
  l += __shfl_xor(l, 16);
  l += __shfl_xor(l, 32);
  if (g == 0) { msh[wid][p] = m; lsh[wid][p] = l; }
#pragma unroll
  for (int mi = 0; mi < 4; ++mi)
#pragma unroll
    for (int r = 0; r < 4; ++r) osh[wid][16 * mi + 4 * g + r][p] = o[mi][r];
  __syncthreads();

  const int q  = threadIdx.x & 15;
  const int db = threadIdx.x >> 4;
  float mm = fmaxf(fmaxf(msh[0][q], msh[1][q]), fmaxf(msh[2][q], msh[3][q]));
  float L = 0.f, a0 = 0.f, a1 = 0.f, a2 = 0.f, a3 = 0.f;
#pragma unroll
  for (int wv = 0; wv < 4; ++wv) {
    float sc = fexp2(msh[wv][q] - mm);
    L  += lsh[wv][q] * sc;
    a0 += osh[wv][4 * db + 0][q] * sc;
    a1 += osh[wv][4 * db + 1][q] * sc;
    a2 += osh[wv][4 * db + 2][q] * sc;
    a3 += osh[wv][4 * db + 3][q] * sc;
  }
  const float inv = 1.f / L;
  float* op = out + (grow0 + q) * HDIM + 4 * db;
  op[0] = a0 * inv; op[1] = a1 * inv; op[2] = a2 * inv; op[3] = a3 * inv;
}

extern "C" void kernel_launch(void* const* d_in, const int* in_sizes, int n_in,
                              void* d_out, int out_size, void* d_ws, size_t ws_size,
                              hipStream_t stream) {
  const float* x  = (const float*)d_in[0];
  const float* Wq = (const float*)d_in[1];
  const float* Wk = (const float*)d_in[2];
  const float* Wv = (const float*)d_in[3];
  float* outp = (float*)d_out;

  const size_t rows = (size_t)BATCH * SEQ;        // 16384
  unsigned short* qbf = (unsigned short*)d_ws;
  unsigned short* kbf = qbf + rows * HDIM;
  unsigned short* vtb = kbf + rows * HDIM;
  unsigned short* wt  = vtb + rows * HDIM;        // 192*1024 bf16

  wt_kernel<<<dim3(48), dim3(256), 0, stream>>>(Wq, Wk, Wv, wt);
  qkv_mfma_kernel<<<dim3((unsigned)(rows / 32)), dim3(256), 0, stream>>>(x, wt, qbf, kbf, vtb);
  attn_kernel<<<dim3((unsigned)(rows / 16)), dim3(256), 0, stream>>>(qbf, kbf, vtb, outp);
}

// Round 7
// 109.599 us; speedup vs baseline: 1.1024x; 1.0978x over previous
//
#include <hip/hip_runtime.h>
#include <math.h>

#define BATCH 4
#define SEQ   4096
#define EMB   1024
#define HDIM  64

typedef __attribute__((ext_vector_type(8))) short bf16x8;
typedef __attribute__((ext_vector_type(4))) float f32x4;

#define MFMA16(a, b, c) __builtin_amdgcn_mfma_f32_16x16x32_bf16(a, b, c, 0, 0, 0)

__device__ __forceinline__ unsigned short f2bf(float f) {
  unsigned int u = __float_as_uint(f);
  u = (u + 0x7FFFu + ((u >> 16) & 1u)) >> 16;   // RNE
  return (unsigned short)u;
}

__device__ __forceinline__ float fexp2(float x) {  // 2^x, hw v_exp_f32
  float r;
  asm("v_exp_f32 %0, %1" : "=v"(r) : "v"(x));
  return r;
}

// ---------------- W pre-transpose: W[1024][64] f32 x3 -> Wt[192][1024] bf16 --
__global__ __launch_bounds__(256) void wt_kernel(
    const float* __restrict__ Wq, const float* __restrict__ Wk,
    const float* __restrict__ Wv, unsigned short* __restrict__ wt) {
  __shared__ float tile[64][65];
  const int bid = blockIdx.x;           // 48 = 3 matrices x 16 k-tiles
  const int m = bid >> 4, kt = bid & 15;
  const float* W = (m == 0) ? Wq : (m == 1) ? Wk : Wv;
  const int tid = threadIdx.x;
  {
    const int r = tid >> 2, c4 = tid & 3;          // k-row, 16-col group
    const float* src = W + (size_t)(kt * 64 + r) * 64 + c4 * 16;
#pragma unroll
    for (int j = 0; j < 4; ++j) {
      float4 a = *(const float4*)(src + j * 4);
      tile[r][c4 * 16 + j * 4 + 0] = a.x;
      tile[r][c4 * 16 + j * 4 + 1] = a.y;
      tile[r][c4 * 16 + j * 4 + 2] = a.z;
      tile[r][c4 * 16 + j * 4 + 3] = a.w;
    }
  }
  __syncthreads();
  {
    const int col = tid >> 2, kq = tid & 3;        // out col, 16-k group
    unsigned short o[16];
#pragma unroll
    for (int j = 0; j < 16; ++j) o[j] = f2bf(tile[kq * 16 + j][col]);
    unsigned short* dst = wt + (size_t)(m * 64 + col) * 1024 + kt * 64 + kq * 16;
    *(bf16x8*)(dst)     = *(bf16x8*)&o[0];
    *(bf16x8*)(dst + 8) = *(bf16x8*)&o[8];
  }
}

// ---------------- QKV projection via MFMA (round-4 proven version) ----------
// 512 blocks (2/CU): 32-row M-tile x all 192 cols. K chunks of 64, bf16 in
// XOR-swizzled LDS; reg-prefetch of next chunk. Wave w owns cols 48w..48w+47.
// q output additionally scaled by C^-0.5 * log2(e) (attention runs in exp2).
__global__ __launch_bounds__(256) void qkv_mfma_kernel(
    const float* __restrict__ x, const unsigned short* __restrict__ wt,
    unsigned short* __restrict__ qb, unsigned short* __restrict__ kb,
    unsigned short* __restrict__ vt) {
  __shared__ __align__(16) unsigned short xs[32 * 64];   // [row][k] swizzled
  __shared__ __align__(16) unsigned short ws[192 * 64];  // [col][k] swizzled
  const int tid  = threadIdx.x;
  const int lane = tid & 63, wid = tid >> 6;
  const int g = lane >> 4, p = lane & 15;
  const size_t row0 = (size_t)blockIdx.x * 32;

  const int sr = tid >> 3, sc = tid & 7;                 // x: row, 8-k group
  const float* xp = x + (row0 + sr) * EMB + sc * 8;

  f32x4 acc[2][3];
#pragma unroll
  for (int rt = 0; rt < 2; ++rt)
#pragma unroll
    for (int ct = 0; ct < 3; ++ct) acc[rt][ct] = (f32x4){0.f, 0.f, 0.f, 0.f};

  float4 rx[2];
  bf16x8 rw[6];
#pragma unroll
  for (int j = 0; j < 2; ++j) rx[j] = *(const float4*)(xp + j * 4);
#pragma unroll
  for (int it = 0; it < 6; ++it) {
    int i = tid + it * 256, col = i >> 3, cc = i & 7;
    rw[it] = *(const bf16x8*)(wt + (size_t)col * 1024 + cc * 8);
  }

  for (int kc = 0; kc < 16; ++kc) {
    __syncthreads();                       // previous chunk's reads done
#pragma unroll
    for (int j = 0; j < 2; ++j) {
      ushort4 h;
      h.x = f2bf(rx[j].x); h.y = f2bf(rx[j].y);
      h.z = f2bf(rx[j].z); h.w = f2bf(rx[j].w);
      *(ushort4*)((char*)xs + ((sr * 128 + sc * 16 + j * 8) ^ ((sr & 7) << 4))) = h;
    }
#pragma unroll
    for (int it = 0; it < 6; ++it) {
      int i = tid + it * 256, col = i >> 3, cc = i & 7;
      *(bf16x8*)((char*)ws + ((col * 128 + cc * 16) ^ ((col & 7) << 4))) = rw[it];
    }
    if (kc < 15) {
      const float* xpn = xp + (kc + 1) * 64;
#pragma unroll
      for (int j = 0; j < 2; ++j) rx[j] = *(const float4*)(xpn + j * 4);
#pragma unroll
      for (int it = 0; it < 6; ++it) {
        int i = tid + it * 256, col = i >> 3, cc = i & 7;
        rw[it] = *(const bf16x8*)(wt + (size_t)col * 1024 + (kc + 1) * 64 + cc * 8);
      }
    }
    __syncthreads();
#pragma unroll
    for (int ks = 0; ks < 2; ++ks) {
      bf16x8 af[2];
#pragma unroll
      for (int rt = 0; rt < 2; ++rt) {
        int row = rt * 16 + p;
        af[rt] = *(const bf16x8*)((char*)xs +
                 ((row * 128 + ks * 64 + g * 16) ^ ((row & 7) << 4)));
      }
#pragma unroll
      for (int ct = 0; ct < 3; ++ct) {
        int col = wid * 48 + ct * 16 + p;
        bf16x8 bfr = *(const bf16x8*)((char*)ws +
                     ((col * 128 + ks * 64 + g * 16) ^ ((col & 7) << 4)));
#pragma unroll
        for (int rt = 0; rt < 2; ++rt)
          acc[rt][ct] = MFMA16(af[rt], bfr, acc[rt][ct]);
      }
    }
  }

  const int b     = (int)(row0 >> 12);
  const int tbase = (int)(row0 & 4095);
  unsigned short* vtb = vt + (((size_t)b * 64 + (tbase >> 6)) * 64) * 64 + (tbase & 63);
#pragma unroll
  for (int rt = 0; rt < 2; ++rt)
#pragma unroll
    for (int ct = 0; ct < 3; ++ct) {
      const int c0  = wid * 48 + ct * 16;
      const int mtx = c0 >> 6;
      const int col = (c0 & 63) + p;
#pragma unroll
      for (int r = 0; r < 4; ++r) {
        const int row = rt * 16 + 4 * g + r;
        const float vf = acc[rt][ct][r];
        if (mtx == 0)      qb[(row0 + row) * HDIM + col] = f2bf(vf * 0.0450843714f);
        else if (mtx == 1) kb[(row0 + row) * HDIM + col] = f2bf(vf);
        else               vtb[(size_t)col * 64 + row]   = f2bf(vf);
      }
    }
}

// ---------------- MFMA flash attention: round-4 structure, split-K x8 -------
// Block = 8 waves sharing 16 queries; wave wid takes key tiles kt=wid,wid+8,...
// merged via LDS at block end. 1024 blocks x 512 thr = 8192 waves (32/CU cap).
// exp2-domain softmax (scale*log2e folded into q), defer-max (T13),
// shuffle-based P^T transpose. Round-4 bid->w mapping (batch-parity complement).
__global__ __launch_bounds__(512) void attn_kernel(
    const unsigned short* __restrict__ qb, const unsigned short* __restrict__ kbm,
    const unsigned short* __restrict__ vt, float* __restrict__ out) {
  __shared__ float msh[8][16], lsh[8][16];
  __shared__ float osh[8][64][17];
  const int wid  = threadIdx.x >> 6;            // 0..7
  const int lane = threadIdx.x & 63;
  const int g = lane >> 4, p = lane & 15;
  const int bid = blockIdx.x, batch = bid >> 8;
  int w = bid & 255;
  if (batch & 1) w = 255 - w;                   // causal load balance
  const int tq0 = w * 16;
  const size_t grow0 = (size_t)batch * SEQ + tq0;
  const int kbd = w >> 2;                       // diagonal 64-key tile

  const unsigned short* qrow = qb + (grow0 + p) * HDIM;
  const bf16x8 qf0 = *(const bf16x8*)(qrow + 8 * g);
  const bf16x8 qf1 = *(const bf16x8*)(qrow + 32 + 8 * g);

  const unsigned short* kbase = kbm + (size_t)batch * SEQ * HDIM;
  const unsigned short* vbase = vt  + (size_t)batch * SEQ * HDIM;

  const int srcA = (g & 1) * 32 + p;
  const int srcB = srcA + 16;
  const bool hi = (g >> 1) != 0;

  float m = -1e30f, l = 0.f;
  f32x4 o[4];
#pragma unroll
  for (int mi = 0; mi < 4; ++mi) o[mi] = (f32x4){0.f, 0.f, 0.f, 0.f};

  for (int kt = wid; kt <= kbd; kt += 8) {
    // ---- S^T = K . Q^T over 64 keys (log2 domain) ----
    const unsigned short* kp = kbase + ((size_t)(kt * 64 + p)) * HDIM + 8 * g;
    f32x4 s[4];
#pragma unroll
    for (int t = 0; t < 4; ++t) {
      bf16x8 a0 = *(const bf16x8*)(kp + t * 1024);
      bf16x8 a1 = *(const bf16x8*)(kp + t * 1024 + 32);
      f32x4 a = (f32x4){0.f, 0.f, 0.f, 0.f};
      a = MFMA16(a0, qf0, a);
      a = MFMA16(a1, qf1, a);
      s[t] = a;
    }
    // ---- causal mask (diag tile only) ----
    if (kt == kbd) {
#pragma unroll
      for (int t = 0; t < 4; ++t)
#pragma unroll
        for (int r = 0; r < 4; ++r) {
          int key = kt * 64 + 16 * t + 4 * g + r;
          if (key > tq0 + p) s[t][r] = -1e30f;
        }
    }
    // ---- tile max ----
    float tm = -3e38f;
#pragma unroll
    for (int t = 0; t < 4; ++t)
#pragma unroll
      for (int r = 0; r < 4; ++r) tm = fmaxf(tm, s[t][r]);
    tm = fmaxf(tm, __shfl_xor(tm, 16));
    tm = fmaxf(tm, __shfl_xor(tm, 32));
    // ---- defer-max (T13) ----
    if (__any(tm > m + 11.5f)) {
      float mn = fmaxf(m, tm);
      float c = fexp2(m - mn);
      l *= c;
#pragma unroll
      for (int mi = 0; mi < 4; ++mi) o[mi] *= c;
      m = mn;
    }
    // ---- P = exp2(S - m) ----
    float psum = 0.f;
#pragma unroll
    for (int t = 0; t < 4; ++t)
#pragma unroll
      for (int r = 0; r < 4; ++r) {
        float pv = fexp2(s[t][r] - m);
        s[t][r] = pv;
        psum += pv;
      }
    l += psum;
    // ---- P^T -> B-operand fragments via shuffles ----
    bf16x8 b0, b1;
#pragma unroll
    for (int r = 0; r < 4; ++r) {
      float v0 = __shfl(s[0][r], srcA), v1 = __shfl(s[1][r], srcA);
      float v2 = __shfl(s[0][r], srcB), v3 = __shfl(s[1][r], srcB);
      b0[r]     = (short)f2bf(hi ? v1 : v0);
      b0[4 + r] = (short)f2bf(hi ? v3 : v2);
      float u0 = __shfl(s[2][r], srcA), u1 = __shfl(s[3][r], srcA);
      float u2 = __shfl(s[2][r], srcB), u3 = __shfl(s[3][r], srcB);
      b1[r]     = (short)f2bf(hi ? u1 : u0);
      b1[4 + r] = (short)f2bf(hi ? u3 : u2);
    }
    // ---- O^T += V^T . P^T ----
    const unsigned short* vp = vbase + (size_t)kt * 4096 + p * 64 + 8 * g;
#pragma unroll
    for (int mi = 0; mi < 4; ++mi) {
      bf16x8 va0 = *(const bf16x8*)(vp + mi * 1024);
      bf16x8 va1 = *(const bf16x8*)(vp + mi * 1024 + 32);
      o[mi] = MFMA16(va0, b0, o[mi]);
      o[mi] = MFMA16(va1, b1, o[mi]);
    }
  }

  // ---- merge the 8 key-split partials (log2-domain maxes) ----
  l += __shfl_xor(l, 16);
  l += __shfl_xor(l, 32);
  if (g == 0) { msh[wid][p] = m; lsh[wid][p] = l; }
#pragma unroll
  for (int mi = 0; mi < 4; ++mi)
#pragma unroll
    for (int r = 0; r < 4; ++r) osh[wid][16 * mi + 4 * g + r][p] = o[mi][r];
  __syncthreads();

  if (threadIdx.x < 256) {
    const int q  = threadIdx.x & 15;
    const int db = threadIdx.x >> 4;            // 0..15 -> dims 4*db..4*db+3
    float mm = -3e38f;
#pragma unroll
    for (int wv = 0; wv < 8; ++wv) mm = fmaxf(mm, msh[wv][q]);
    float L = 0.f, a0 = 0.f, a1 = 0.f, a2 = 0.f, a3 = 0.f;
#pragma unroll
    for (int wv = 0; wv < 8; ++wv) {
      float sc = fexp2(msh[wv][q] - mm);
      L  += lsh[wv][q] * sc;
      a0 += osh[wv][4 * db + 0][q] * sc;
      a1 += osh[wv][4 * db + 1][q] * sc;
      a2 += osh[wv][4 * db + 2][q] * sc;
      a3 += osh[wv][4 * db + 3][q] * sc;
    }
    const float inv = 1.f / L;
    float* op = out + (grow0 + q) * HDIM + 4 * db;
    op[0] = a0 * inv; op[1] = a1 * inv; op[2] = a2 * inv; op[3] = a3 * inv;
  }
}

extern "C" void kernel_launch(void* const* d_in, const int* in_sizes, int n_in,
                              void* d_out, int out_size, void* d_ws, size_t ws_size,
                              hipStream_t stream) {
  const float* x  = (const float*)d_in[0];
  const float* Wq = (const float*)d_in[1];
  const float* Wk = (const float*)d_in[2];
  const float* Wv = (const float*)d_in[3];
  float* outp = (float*)d_out;

  const size_t rows = (size_t)BATCH * SEQ;        // 16384
  unsigned short* qbf = (unsigned short*)d_ws;
  unsigned short* kbf = qbf + rows * HDIM;
  unsigned short* vtb = kbf + rows * HDIM;
  unsigned short* wt  = vtb + rows * HDIM;        // 192*1024 bf16

  wt_kernel<<<dim3(48), dim3(256), 0, stream>>>(Wq, Wk, Wv, wt);
  qkv_mfma_kernel<<<dim3((unsigned)(rows / 32)), dim3(256), 0, stream>>>(x, wt, qbf, kbf, vtb);
  attn_kernel<<<dim3((unsigned)(rows / 16)), dim3(512), 0, stream>>>(qbf, kbf, vtb, outp);
}

// Round 8
// 92.549 us; speedup vs baseline: 1.3055x; 1.1842x over previous
//
#include <hip/hip_runtime.h>
#include <math.h>

#define BATCH 4
#define SEQ   4096
#define EMB   1024
#define HDIM  64

typedef __attribute__((ext_vector_type(8))) short bf16x8;
typedef __attribute__((ext_vector_type(4))) float f32x4;

#define MFMA16(a, b, c) __builtin_amdgcn_mfma_f32_16x16x32_bf16(a, b, c, 0, 0, 0)

__device__ __forceinline__ unsigned short f2bf(float f) {
  unsigned int u = __float_as_uint(f);
  u = (u + 0x7FFFu + ((u >> 16) & 1u)) >> 16;   // RNE
  return (unsigned short)u;
}

__device__ __forceinline__ float fexp2(float x) {  // 2^x, hw v_exp_f32
  float r;
  asm("v_exp_f32 %0, %1" : "=v"(r) : "v"(x));
  return r;
}

// ---------------- W pre-transpose: W[1024][64] f32 x3 -> Wt[192][1024] bf16 --
__global__ __launch_bounds__(256) void wt_kernel(
    const float* __restrict__ Wq, const float* __restrict__ Wk,
    const float* __restrict__ Wv, unsigned short* __restrict__ wt) {
  __shared__ float tile[64][65];
  const int bid = blockIdx.x;           // 48 = 3 matrices x 16 k-tiles
  const int m = bid >> 4, kt = bid & 15;
  const float* W = (m == 0) ? Wq : (m == 1) ? Wk : Wv;
  const int tid = threadIdx.x;
  {
    const int r = tid >> 2, c4 = tid & 3;          // k-row, 16-col group
    const float* src = W + (size_t)(kt * 64 + r) * 64 + c4 * 16;
#pragma unroll
    for (int j = 0; j < 4; ++j) {
      float4 a = *(const float4*)(src + j * 4);
      tile[r][c4 * 16 + j * 4 + 0] = a.x;
      tile[r][c4 * 16 + j * 4 + 1] = a.y;
      tile[r][c4 * 16 + j * 4 + 2] = a.z;
      tile[r][c4 * 16 + j * 4 + 3] = a.w;
    }
  }
  __syncthreads();
  {
    const int col = tid >> 2, kq = tid & 3;        // out col, 16-k group
    unsigned short o[16];
#pragma unroll
    for (int j = 0; j < 16; ++j) o[j] = f2bf(tile[kq * 16 + j][col]);
    unsigned short* dst = wt + (size_t)(m * 64 + col) * 1024 + kt * 64 + kq * 16;
    *(bf16x8*)(dst)     = *(bf16x8*)&o[0];
    *(bf16x8*)(dst + 8) = *(bf16x8*)&o[8];
  }
}

// ---------------- QKV projection via MFMA (round-4 proven version) ----------
__global__ __launch_bounds__(256) void qkv_mfma_kernel(
    const float* __restrict__ x, const unsigned short* __restrict__ wt,
    unsigned short* __restrict__ qb, unsigned short* __restrict__ kb,
    unsigned short* __restrict__ vt) {
  __shared__ __align__(16) unsigned short xs[32 * 64];   // [row][k] swizzled
  __shared__ __align__(16) unsigned short ws[192 * 64];  // [col][k] swizzled
  const int tid  = threadIdx.x;
  const int lane = tid & 63, wid = tid >> 6;
  const int g = lane >> 4, p = lane & 15;
  const size_t row0 = (size_t)blockIdx.x * 32;

  const int sr = tid >> 3, sc = tid & 7;                 // x: row, 8-k group
  const float* xp = x + (row0 + sr) * EMB + sc * 8;

  f32x4 acc[2][3];
#pragma unroll
  for (int rt = 0; rt < 2; ++rt)
#pragma unroll
    for (int ct = 0; ct < 3; ++ct) acc[rt][ct] = (f32x4){0.f, 0.f, 0.f, 0.f};

  float4 rx[2];
  bf16x8 rw[6];
#pragma unroll
  for (int j = 0; j < 2; ++j) rx[j] = *(const float4*)(xp + j * 4);
#pragma unroll
  for (int it = 0; it < 6; ++it) {
    int i = tid + it * 256, col = i >> 3, cc = i & 7;
    rw[it] = *(const bf16x8*)(wt + (size_t)col * 1024 + cc * 8);
  }

  for (int kc = 0; kc < 16; ++kc) {
    __syncthreads();                       // previous chunk's reads done
#pragma unroll
    for (int j = 0; j < 2; ++j) {
      ushort4 h;
      h.x = f2bf(rx[j].x); h.y = f2bf(rx[j].y);
      h.z = f2bf(rx[j].z); h.w = f2bf(rx[j].w);
      *(ushort4*)((char*)xs + ((sr * 128 + sc * 16 + j * 8) ^ ((sr & 7) << 4))) = h;
    }
#pragma unroll
    for (int it = 0; it < 6; ++it) {
      int i = tid + it * 256, col = i >> 3, cc = i & 7;
      *(bf16x8*)((char*)ws + ((col * 128 + cc * 16) ^ ((col & 7) << 4))) = rw[it];
    }
    if (kc < 15) {
      const float* xpn = xp + (kc + 1) * 64;
#pragma unroll
      for (int j = 0; j < 2; ++j) rx[j] = *(const float4*)(xpn + j * 4);
#pragma unroll
      for (int it = 0; it < 6; ++it) {
        int i = tid + it * 256, col = i >> 3, cc = i & 7;
        rw[it] = *(const bf16x8*)(wt + (size_t)col * 1024 + (kc + 1) * 64 + cc * 8);
      }
    }
    __syncthreads();
#pragma unroll
    for (int ks = 0; ks < 2; ++ks) {
      bf16x8 af[2];
#pragma unroll
      for (int rt = 0; rt < 2; ++rt) {
        int row = rt * 16 + p;
        af[rt] = *(const bf16x8*)((char*)xs +
                 ((row * 128 + ks * 64 + g * 16) ^ ((row & 7) << 4)));
      }
#pragma unroll
      for (int ct = 0; ct < 3; ++ct) {
        int col = wid * 48 + ct * 16 + p;
        bf16x8 bfr = *(const bf16x8*)((char*)ws +
                     ((col * 128 + ks * 64 + g * 16) ^ ((col & 7) << 4)));
#pragma unroll
        for (int rt = 0; rt < 2; ++rt)
          acc[rt][ct] = MFMA16(af[rt], bfr, acc[rt][ct]);
      }
    }
  }

  const int b     = (int)(row0 >> 12);
  const int tbase = (int)(row0 & 4095);
  unsigned short* vtb = vt + (((size_t)b * 64 + (tbase >> 6)) * 64) * 64 + (tbase & 63);
#pragma unroll
  for (int rt = 0; rt < 2; ++rt)
#pragma unroll
    for (int ct = 0; ct < 3; ++ct) {
      const int c0  = wid * 48 + ct * 16;
      const int mtx = c0 >> 6;
      const int col = (c0 & 63) + p;
#pragma unroll
      for (int r = 0; r < 4; ++r) {
        const int row = rt * 16 + 4 * g + r;
        const float vf = acc[rt][ct][r];
        if (mtx == 0)      qb[(row0 + row) * HDIM + col] = f2bf(vf * 0.0450843714f);
        else if (mtx == 1) kb[(row0 + row) * HDIM + col] = f2bf(vf);
        else               vtb[(size_t)col * 64 + row]   = f2bf(vf);
      }
    }
}

// ---- one 64-key attention tile (round-4 proven body, parameterized) --------
__device__ __forceinline__ void attn_tile(
    const unsigned short* __restrict__ kbase,
    const unsigned short* __restrict__ vbase,
    int kt, int tq0, bool diag,
    const bf16x8& qf0, const bf16x8& qf1,
    int p, int g, int srcA, int srcB, bool hi,
    float& m, float& l, f32x4 (&o)[4]) {
  const unsigned short* kp = kbase + ((size_t)(kt * 64 + p)) * HDIM + 8 * g;
  f32x4 s[4];
#pragma unroll
  for (int t = 0; t < 4; ++t) {
    bf16x8 a0 = *(const bf16x8*)(kp + t * 1024);
    bf16x8 a1 = *(const bf16x8*)(kp + t * 1024 + 32);
    f32x4 a = (f32x4){0.f, 0.f, 0.f, 0.f};
    a = MFMA16(a0, qf0, a);
    a = MFMA16(a1, qf1, a);
    s[t] = a;
  }
  if (diag) {
#pragma unroll
    for (int t = 0; t < 4; ++t)
#pragma unroll
      for (int r = 0; r < 4; ++r) {
        int key = kt * 64 + 16 * t + 4 * g + r;
        if (key > tq0 + p) s[t][r] = -1e30f;
      }
  }
  float tm = -3e38f;
#pragma unroll
  for (int t = 0; t < 4; ++t)
#pragma unroll
    for (int r = 0; r < 4; ++r) tm = fmaxf(tm, s[t][r]);
  tm = fmaxf(tm, __shfl_xor(tm, 16));
  tm = fmaxf(tm, __shfl_xor(tm, 32));
  if (__any(tm > m + 11.5f)) {               // defer-max (T13)
    float mn = fmaxf(m, tm);
    float c = fexp2(m - mn);
    l *= c;
#pragma unroll
    for (int mi = 0; mi < 4; ++mi) o[mi] *= c;
    m = mn;
  }
  float psum = 0.f;
#pragma unroll
  for (int t = 0; t < 4; ++t)
#pragma unroll
    for (int r = 0; r < 4; ++r) {
      float pv = fexp2(s[t][r] - m);
      s[t][r] = pv;
      psum += pv;
    }
  l += psum;
  bf16x8 b0, b1;
#pragma unroll
  for (int r = 0; r < 4; ++r) {
    float v0 = __shfl(s[0][r], srcA), v1 = __shfl(s[1][r], srcA);
    float v2 = __shfl(s[0][r], srcB), v3 = __shfl(s[1][r], srcB);
    b0[r]     = (short)f2bf(hi ? v1 : v0);
    b0[4 + r] = (short)f2bf(hi ? v3 : v2);
    float u0 = __shfl(s[2][r], srcA), u1 = __shfl(s[3][r], srcA);
    float u2 = __shfl(s[2][r], srcB), u3 = __shfl(s[3][r], srcB);
    b1[r]     = (short)f2bf(hi ? u1 : u0);
    b1[4 + r] = (short)f2bf(hi ? u3 : u2);
  }
  const unsigned short* vp = vbase + (size_t)kt * 4096 + p * 64 + 8 * g;
#pragma unroll
  for (int mi = 0; mi < 4; ++mi) {
    bf16x8 va0 = *(const bf16x8*)(vp + mi * 1024);
    bf16x8 va1 = *(const bf16x8*)(vp + mi * 1024 + 32);
    o[mi] = MFMA16(va0, b0, o[mi]);
    o[mi] = MFMA16(va1, b1, o[mi]);
  }
}

// ---- MFMA flash attention: equal-work paired blocks ------------------------
// Block = 8 waves, TWO query groups: wA=bid&127 and wB=255-wA (same batch).
// Combined tile list nA+nB == 65 always -> every block identical work; wave
// wid takes items wid, wid+8,... keeping separate (m,l,o) state per group.
// 512 blocks = 2/CU, all finish together. Merge 8 partials per group via LDS
// (one osh buffer reused in two phases).
__global__ __launch_bounds__(512, 4) void attn_kernel(
    const unsigned short* __restrict__ qb, const unsigned short* __restrict__ kbm,
    const unsigned short* __restrict__ vt, float* __restrict__ out) {
  __shared__ float msh[8][16], lsh[8][16];
  __shared__ float osh[8][64][17];
  const int wid  = threadIdx.x >> 6;            // 0..7
  const int lane = threadIdx.x & 63;
  const int g = lane >> 4, p = lane & 15;
  const int bid = blockIdx.x;
  const int batch = bid >> 7;                   // 128 pair-blocks per batch
  const int wA = bid & 127, wB = 255 - wA;
  const int tq0A = wA * 16, tq0B = wB * 16;
  const size_t grow0A = (size_t)batch * SEQ + tq0A;
  const size_t grow0B = (size_t)batch * SEQ + tq0B;
  const int nA = (wA >> 2) + 1;                 // 1..32
  const int nB = (wB >> 2) + 1;                 // 33..64 ; nA+nB == 65

  const unsigned short* kbase = kbm + (size_t)batch * SEQ * HDIM;
  const unsigned short* vbase = vt  + (size_t)batch * SEQ * HDIM;

  const unsigned short* qrowA = qb + (grow0A + p) * HDIM;
  const bf16x8 qfA0 = *(const bf16x8*)(qrowA + 8 * g);
  const bf16x8 qfA1 = *(const bf16x8*)(qrowA + 32 + 8 * g);
  const unsigned short* qrowB = qb + (grow0B + p) * HDIM;
  const bf16x8 qfB0 = *(const bf16x8*)(qrowB + 8 * g);
  const bf16x8 qfB1 = *(const bf16x8*)(qrowB + 32 + 8 * g);

  const int srcA = (g & 1) * 32 + p;
  const int srcB = srcA + 16;
  const bool hi = (g >> 1) != 0;

  float mA = -1e30f, lA = 0.f, mB = -1e30f, lB = 0.f;
  f32x4 oA[4], oB[4];
#pragma unroll
  for (int mi = 0; mi < 4; ++mi) {
    oA[mi] = (f32x4){0.f, 0.f, 0.f, 0.f};
    oB[mi] = (f32x4){0.f, 0.f, 0.f, 0.f};
  }

  for (int it = wid; it < 65; it += 8) {
    if (it < nA) {
      attn_tile(kbase, vbase, it, tq0A, it == nA - 1, qfA0, qfA1,
                p, g, srcA, srcB, hi, mA, lA, oA);
    } else {
      const int kt = it - nA;
      attn_tile(kbase, vbase, kt, tq0B, kt == nB - 1, qfB0, qfB1,
                p, g, srcA, srcB, hi, mB, lB, oB);
    }
  }

  lA += __shfl_xor(lA, 16); lA += __shfl_xor(lA, 32);
  lB += __shfl_xor(lB, 16); lB += __shfl_xor(lB, 32);

  // ---- merge group A ----
  if (g == 0) { msh[wid][p] = mA; lsh[wid][p] = lA; }
#pragma unroll
  for (int mi = 0; mi < 4; ++mi)
#pragma unroll
    for (int r = 0; r < 4; ++r) osh[wid][16 * mi + 4 * g + r][p] = oA[mi][r];
  __syncthreads();
  if (threadIdx.x < 256) {
    const int q  = threadIdx.x & 15;
    const int db = threadIdx.x >> 4;
    float mm = -3e38f;
#pragma unroll
    for (int wv = 0; wv < 8; ++wv) mm = fmaxf(mm, msh[wv][q]);
    float L = 0.f, a0 = 0.f, a1 = 0.f, a2 = 0.f, a3 = 0.f;
#pragma unroll
    for (int wv = 0; wv < 8; ++wv) {
      float sc = fexp2(msh[wv][q] - mm);
      L  += lsh[wv][q] * sc;
      a0 += osh[wv][4 * db + 0][q] * sc;
      a1 += osh[wv][4 * db + 1][q] * sc;
      a2 += osh[wv][4 * db + 2][q] * sc;
      a3 += osh[wv][4 * db + 3][q] * sc;
    }
    const float inv = 1.f / L;
    float* op = out + (grow0A + q) * HDIM + 4 * db;
    op[0] = a0 * inv; op[1] = a1 * inv; op[2] = a2 * inv; op[3] = a3 * inv;
  }
  __syncthreads();

  // ---- merge group B ----
  if (g == 0) { msh[wid][p] = mB; lsh[wid][p] = lB; }
#pragma unroll
  for (int mi = 0; mi < 4; ++mi)
#pragma unroll
    for (int r = 0; r < 4; ++r) osh[wid][16 * mi + 4 * g + r][p] = oB[mi][r];
  __syncthreads();
  if (threadIdx.x < 256) {
    const int q  = threadIdx.x & 15;
    const int db = threadIdx.x >> 4;
    float mm = -3e38f;
#pragma unroll
    for (int wv = 0; wv < 8; ++wv) mm = fmaxf(mm, msh[wv][q]);
    float L = 0.f, a0 = 0.f, a1 = 0.f, a2 = 0.f, a3 = 0.f;
#pragma unroll
    for (int wv = 0; wv < 8; ++wv) {
      float sc = fexp2(msh[wv][q] - mm);
      L  += lsh[wv][q] * sc;
      a0 += osh[wv][4 * db + 0][q] * sc;
      a1 += osh[wv][4 * db + 1][q] * sc;
      a2 += osh[wv][4 * db + 2][q] * sc;
      a3 += osh[wv][4 * db + 3][q] * sc;
    }
    const float inv = 1.f / L;
    float* op = out + (grow0B + q) * HDIM + 4 * db;
    op[0] = a0 * inv; op[1] = a1 * inv; op[2] = a2 * inv; op[3] = a3 * inv;
  }
}

extern "C" void kernel_launch(void* const* d_in, const int* in_sizes, int n_in,
                              void* d_out, int out_size, void* d_ws, size_t ws_size,
                              hipStream_t stream) {
  const float* x  = (const float*)d_in[0];
  const float* Wq = (const float*)d_in[1];
  const float* Wk = (const float*)d_in[2];
  const float* Wv = (const float*)d_in[3];
  float* outp = (float*)d_out;

  const size_t rows = (size_t)BATCH * SEQ;        // 16384
  unsigned short* qbf = (unsigned short*)d_ws;
  unsigned short* kbf = qbf + rows * HDIM;
  unsigned short* vtb = kbf + rows * HDIM;
  unsigned short* wt  = vtb + rows * HDIM;        // 192*1024 bf16

  wt_kernel<<<dim3(48), dim3(256), 0, stream>>>(Wq, Wk, Wv, wt);
  qkv_mfma_kernel<<<dim3((unsigned)(rows / 32)), dim3(256), 0, stream>>>(x, wt, qbf, kbf, vtb);
  attn_kernel<<<dim3(512), dim3(512), 0, stream>>>(qbf, kbf, vtb, outp);
}